// Round 1
// baseline (1098.930 us; speedup 1.0000x reference)
//
#include <hip/hip_runtime.h>
#include <hip/hip_bf16.h>
#include <hip/hip_fp16.h>

typedef unsigned int u32;
typedef unsigned short u16;
typedef short s16x8 __attribute__((ext_vector_type(8)));
typedef float f32x4 __attribute__((ext_vector_type(4)));
typedef _Float16 f16x2 __attribute__((ext_vector_type(2)));

#define T_STEPS 256

// ---------------- helpers ----------------
__device__ __forceinline__ u16 f2bu(float f) {
  return __bfloat16_as_ushort(__float2bfloat16(f));
}
__device__ __forceinline__ float fast_tanh(float x) {
  float ax = fabsf(x);
  float e = __expf(-2.f * ax);
  float r = 1.f - 2.f * e / (1.f + e);
  return copysignf(r, x);
}
__device__ __forceinline__ float fdot2u(u32 w, u32 h, float acc) {
#if __has_builtin(__builtin_amdgcn_fdot2)
  return __builtin_amdgcn_fdot2(__builtin_bit_cast(f16x2, w),
                                __builtin_bit_cast(f16x2, h), acc, false);
#else
  float w0 = __half2float(__ushort_as_half((u16)(w & 0xffff)));
  float w1 = __half2float(__ushort_as_half((u16)(w >> 16)));
  float g0 = __half2float(__ushort_as_half((u16)(h & 0xffff)));
  float g1 = __half2float(__ushort_as_half((u16)(h >> 16)));
  return acc + w0 * g0 + w1 * g1;
#endif
}
__device__ __forceinline__ void gload_lds16(const void* g, void* l) {
  __builtin_amdgcn_global_load_lds((const __attribute__((address_space(1))) u32*)g,
                                   (__attribute__((address_space(3))) u32*)l, 16, 0, 0);
}

// ---------------- x f32 -> bf16 ----------------
__global__ void k_cvt_bf16(const float* __restrict__ in, u16* __restrict__ out, int n4) {
  int i = blockIdx.x * blockDim.x + threadIdx.x;
  if (i >= n4) return;
  const float4 v = ((const float4*)in)[i];
  ushort4 o;
  o.x = f2bu(v.x); o.y = f2bu(v.y); o.z = f2bu(v.z); o.w = f2bu(v.w);
  ((ushort4*)out)[i] = o;
}

// ---------------- weight prep (per layer) ----------------
// BcatT [1024][512] bf16: BcatT[n][k] = (n<512 ? Wh[k][n] : Wo[k][n-512])   (x-part, transposed)
// WhoT  [512][512]  bf16: WhoT[n][k]  = Wo[512+k][n]                        (h-part of Wo, transposed)
// Wpack [256][512]  f16x2: Wpack[k2][j] = (Wh[512+2k2][j], Wh[512+2k2+1][j]) (h-part of Wh, k-paired)
__global__ void k_prep_w(const float* __restrict__ Wh, const float* __restrict__ Wo,
                         u16* __restrict__ BcatT, u16* __restrict__ WhoT,
                         u32* __restrict__ Wpack) {
  int idx = blockIdx.x * 256 + threadIdx.x;
  if (idx < 1024 * 512) {
    int n = idx >> 9, k = idx & 511;
    float v = (n < 512) ? Wh[k * 512 + n] : Wo[k * 512 + (n - 512)];
    BcatT[idx] = f2bu(v);
  } else if (idx < 1024 * 512 + 512 * 512) {
    int t = idx - 1024 * 512;
    int n = t >> 9, k = t & 511;
    WhoT[t] = f2bu(Wo[(512 + k) * 512 + n]);
  } else {
    int t = idx - (1024 * 512 + 512 * 512);
    int k2 = t >> 9, j = t & 511;
    u16 a = __half_as_ushort(__float2half(Wh[(512 + 2 * k2) * 512 + j]));
    u16 b = __half_as_ushort(__float2half(Wh[(512 + 2 * k2 + 1) * 512 + j]));
    Wpack[t] = (u32)a | ((u32)b << 16);
  }
}

// ---------------- bf16 MFMA GEMM: C[M x N] = A[M x 512] * BT[N x 512]^T ----------------
// MODE 0: outH[row*1024+col] = f16(acc + bias)        (bias = col<512 ? biasH : biasO)
// MODE 1: outB[row*512+col]  = bf16(tanh(acc + Uo[row*1024+col]))
// MODE 2: outF[row*512+col]  = tanh(acc + Uo[row*1024+col])
template <int MODE>
__global__ __launch_bounds__(256) void k_gemm(
    const u16* __restrict__ A, const u16* __restrict__ BT, int NX,
    __half* __restrict__ outH, u16* __restrict__ outB, float* __restrict__ outF,
    const __half* __restrict__ Uo, const float* __restrict__ biasH,
    const float* __restrict__ biasO) {
  __shared__ __align__(16) u16 As[128 * 64], Bs[128 * 64];
  const int bid = blockIdx.x;
  const int bn = bid % NX, bm = bid / NX;
  const int m0 = bm * 128, n0 = bn * 128;
  const int tid = threadIdx.x, w = tid >> 6, l = tid & 63;
  const int l15 = l & 15, lk = (l >> 4) << 3;
  f32x4 acc[4][4] = {};
  for (int kt = 0; kt < 8; ++kt) {
    const int k0 = kt * 64;
#pragma unroll
    for (int i = 0; i < 4; ++i) {
      int idx = w * 4 + i;
      int ob = idx * 1024 + l * 16;
      int row = ob >> 7, cb = ob & 127;
      int scb = cb ^ ((row & 7) << 4);  // pre-swizzled global source (T2 both-sides rule)
      gload_lds16((const char*)A + (size_t)(m0 + row) * 1024 + k0 * 2 + scb,
                  (char*)As + idx * 1024);
      gload_lds16((const char*)BT + (size_t)(n0 + row) * 1024 + k0 * 2 + scb,
                  (char*)Bs + idx * 1024);
    }
    __syncthreads();
    const int wr = (w >> 1) * 64, wc = (w & 1) * 64;
#pragma unroll
    for (int kk = 0; kk < 2; ++kk) {
      s16x8 af[4], bfr[4];
      const int kb = (kk * 32 + lk) * 2;
#pragma unroll
      for (int i = 0; i < 4; ++i) {
        int ar = wr + i * 16 + l15;
        af[i] = *(const s16x8*)((const char*)As + ar * 128 + (kb ^ ((ar & 7) << 4)));
        int br = wc + i * 16 + l15;
        bfr[i] = *(const s16x8*)((const char*)Bs + br * 128 + (kb ^ ((br & 7) << 4)));
      }
#pragma unroll
      for (int i = 0; i < 4; ++i)
#pragma unroll
        for (int jj = 0; jj < 4; ++jj)
          acc[i][jj] = __builtin_amdgcn_mfma_f32_16x16x32_bf16(af[i], bfr[jj], acc[i][jj], 0, 0, 0);
    }
    __syncthreads();
  }
#pragma unroll
  for (int i = 0; i < 4; ++i)
#pragma unroll
    for (int jj = 0; jj < 4; ++jj)
#pragma unroll
      for (int rr = 0; rr < 4; ++rr) {
        int row = m0 + (w >> 1) * 64 + i * 16 + ((l >> 4) << 2) + rr;
        int col = n0 + (w & 1) * 64 + jj * 16 + l15;
        float v = acc[i][jj][rr];
        if (MODE == 0) {
          float bsv = (col < 512) ? biasH[col] : biasO[col - 512];
          outH[(size_t)row * 1024 + col] = __float2half(v + bsv);
        } else {
          float o = fast_tanh(v + __half2float(Uo[(size_t)row * 1024 + col]));
          if (MODE == 1) outB[(size_t)row * 512 + col] = f2bu(o);
          else           outF[(size_t)row * 512 + col] = o;
        }
      }
}

// ---------------- recurrent scan: one workgroup per batch row ----------------
// h' = tanh(Uh[t] + h @ Whh);  stores h_in[t] (pre-update) as bf16 into Hseq.
// Whh (f16, k-paired) residency: 192 pairs in VGPRs, 28 pairs in LDS, 36 streamed from L2.
#define REG_G 48  // 192 k2-pairs in registers
#define LDS_G 7   // 28 pairs in LDS (56KB)
#define STR_G 9   // 36 pairs streamed per step

__global__ __launch_bounds__(512, 2) void k_scan(
    const u32* __restrict__ Wpack, const __half* __restrict__ Uh,
    const float* __restrict__ h0, u16* __restrict__ Hseq) {
  __shared__ u32 Wlds[LDS_G * 4 * 512];
  __shared__ __align__(16) __half hbuf[512];
  const int b = blockIdx.x, j = threadIdx.x;
  u32 wreg[REG_G * 4];
#pragma unroll
  for (int p = 0; p < REG_G * 4; ++p) wreg[p] = Wpack[p * 512 + j];
#pragma unroll
  for (int p = 0; p < LDS_G * 4; ++p) Wlds[p * 512 + j] = Wpack[(REG_G * 4 + p) * 512 + j];
  float h = h0 ? h0[b * 512 + j] : 0.f;
  hbuf[j] = __float2half(h);
  __syncthreads();
  const uint4* h4 = (const uint4*)hbuf;
  int r = b * T_STEPS;
  for (int t = 0; t < T_STEPS; ++t, ++r) {
    u32 wst[STR_G * 4];
#pragma unroll
    for (int p = 0; p < STR_G * 4; ++p)
      wst[p] = Wpack[((REG_G + LDS_G) * 4 + p) * 512 + j];
    float acc = __half2float(Uh[r * 1024 + j]);
    Hseq[r * 512 + j] = f2bu(h);  // h_in at step t
#pragma unroll
    for (int g = 0; g < REG_G; ++g) {
      uint4 hv = h4[g];
      acc = fdot2u(wreg[4 * g + 0], hv.x, acc);
      acc = fdot2u(wreg[4 * g + 1], hv.y, acc);
      acc = fdot2u(wreg[4 * g + 2], hv.z, acc);
      acc = fdot2u(wreg[4 * g + 3], hv.w, acc);
    }
#pragma unroll
    for (int g = 0; g < LDS_G; ++g) {
      uint4 hv = h4[REG_G + g];
      acc = fdot2u(Wlds[(4 * g + 0) * 512 + j], hv.x, acc);
      acc = fdot2u(Wlds[(4 * g + 1) * 512 + j], hv.y, acc);
      acc = fdot2u(Wlds[(4 * g + 2) * 512 + j], hv.z, acc);
      acc = fdot2u(Wlds[(4 * g + 3) * 512 + j], hv.w, acc);
    }
#pragma unroll
    for (int g = 0; g < STR_G; ++g) {
      uint4 hv = h4[REG_G + LDS_G + g];
      acc = fdot2u(wst[4 * g + 0], hv.x, acc);
      acc = fdot2u(wst[4 * g + 1], hv.y, acc);
      acc = fdot2u(wst[4 * g + 2], hv.z, acc);
      acc = fdot2u(wst[4 * g + 3], hv.w, acc);
    }
    float hn = fast_tanh(acc);
    __syncthreads();               // all reads of hbuf done
    hbuf[j] = __float2half(hn);
    h = hn;
    __syncthreads();               // new h visible
  }
}

// ---------------- launch ----------------
extern "C" void kernel_launch(void* const* d_in, const int* in_sizes, int n_in,
                              void* d_out, int out_size, void* d_ws, size_t ws_size,
                              hipStream_t stream) {
  const float* x   = (const float*)d_in[0];
  const float* enc = (const float*)d_in[1];
  const float* Wh0 = (const float*)d_in[2];
  const float* bh0 = (const float*)d_in[3];
  const float* Wo0 = (const float*)d_in[4];
  const float* bo0 = (const float*)d_in[5];
  const float* Wh1 = (const float*)d_in[6];
  const float* bh1 = (const float*)d_in[7];
  const float* Wo1 = (const float*)d_in[8];
  const float* bo1 = (const float*)d_in[9];
  char* ws = (char*)d_ws;
  // ws layout (bytes): Xbf 16MB | U 32MB | Hs0 16MB | Out0 16MB | Hs1 16MB | weights ~4MB  (~100MB)
  u16*    Xbf   = (u16*)(ws);
  __half* U     = (__half*)(ws + 16777216);
  u16*    Hs0   = (u16*)(ws + 16777216 + 33554432);
  u16*    Out0  = (u16*)(ws + 16777216 + 33554432 + 16777216);
  u16*    Hs1   = (u16*)(ws + 16777216 + 33554432 + 2 * 16777216);
  char*   wb    = ws + 16777216 + 33554432 + 3 * 16777216;
  u16*    Bct0  = (u16*)(wb);
  u16*    WhoT0 = (u16*)(wb + 1048576);
  u32*    Wpk0  = (u32*)(wb + 1048576 + 524288);
  u16*    Bct1  = (u16*)(wb + 1048576 + 2 * 524288);
  u16*    WhoT1 = (u16*)(wb + 2 * 1048576 + 2 * 524288);
  u32*    Wpk1  = (u32*)(wb + 2 * 1048576 + 3 * 524288);

  k_cvt_bf16<<<8192, 256, 0, stream>>>(x, Xbf, 8388608 / 4);
  k_prep_w<<<3584, 256, 0, stream>>>(Wh0, Wo0, Bct0, WhoT0, Wpk0);
  k_prep_w<<<3584, 256, 0, stream>>>(Wh1, Wo1, Bct1, WhoT1, Wpk1);
  // U = [x-proj for h | x-proj for o] + biases, layer 0
  k_gemm<0><<<1024, 256, 0, stream>>>(Xbf, Bct0, 8, U, nullptr, nullptr, nullptr, bh0, bo0);
  // layer-0 h-chain
  k_scan<<<64, 512, 0, stream>>>(Wpk0, U, enc, Hs0);
  // out0 = tanh(U_o + Hseq0 @ Who0)
  k_gemm<1><<<512, 256, 0, stream>>>(Hs0, WhoT0, 4, nullptr, Out0, nullptr, U + 512, nullptr, nullptr);
  // layer-1 input projections (reuse U)
  k_gemm<0><<<1024, 256, 0, stream>>>(Out0, Bct1, 8, U, nullptr, nullptr, nullptr, bh1, bo1);
  // layer-1 h-chain (h0 = zeros)
  k_scan<<<64, 512, 0, stream>>>(Wpk1, U, nullptr, Hs1);
  // final: out = tanh(U_o + Hseq1 @ Who1), written straight into [B,T,D] f32
  k_gemm<2><<<512, 256, 0, stream>>>(Hs1, WhoT1, 4, nullptr, nullptr, (float*)d_out, U + 512, nullptr, nullptr);
}

// Round 2
// 1048.279 us; speedup vs baseline: 1.0483x; 1.0483x over previous
//
#include <hip/hip_runtime.h>
#include <hip/hip_bf16.h>
#include <hip/hip_fp16.h>

typedef unsigned int u32;
typedef unsigned short u16;
typedef short s16x8 __attribute__((ext_vector_type(8)));
typedef float f32x4 __attribute__((ext_vector_type(4)));
typedef _Float16 f16x2 __attribute__((ext_vector_type(2)));

#define T_STEPS 256

// ---------------- helpers ----------------
__device__ __forceinline__ u16 f2bu(float f) {
  return __bfloat16_as_ushort(__float2bfloat16(f));
}
__device__ __forceinline__ float fast_tanh(float x) {
  float ax = fabsf(x);
  float e = __expf(-2.f * ax);
  float r = 1.f - 2.f * e / (1.f + e);
  return copysignf(r, x);
}
__device__ __forceinline__ float fdot2u(u32 w, u32 h, float acc) {
#if __has_builtin(__builtin_amdgcn_fdot2)
  return __builtin_amdgcn_fdot2(__builtin_bit_cast(f16x2, w),
                                __builtin_bit_cast(f16x2, h), acc, false);
#else
  float w0 = __half2float(__ushort_as_half((u16)(w & 0xffff)));
  float w1 = __half2float(__ushort_as_half((u16)(w >> 16)));
  float g0 = __half2float(__ushort_as_half((u16)(h & 0xffff)));
  float g1 = __half2float(__ushort_as_half((u16)(h >> 16)));
  return acc + w0 * g0 + w1 * g1;
#endif
}
__device__ __forceinline__ void gload_lds16(const void* g, void* l) {
  __builtin_amdgcn_global_load_lds((const __attribute__((address_space(1))) u32*)g,
                                   (__attribute__((address_space(3))) u32*)l, 16, 0, 0);
}

// ---------------- x f32 -> bf16 ----------------
__global__ void k_cvt_bf16(const float* __restrict__ in, u16* __restrict__ out, int n4) {
  int i = blockIdx.x * blockDim.x + threadIdx.x;
  if (i >= n4) return;
  const float4 v = ((const float4*)in)[i];
  ushort4 o;
  o.x = f2bu(v.x); o.y = f2bu(v.y); o.z = f2bu(v.z); o.w = f2bu(v.w);
  ((ushort4*)out)[i] = o;
}

// ---------------- weight prep (per layer) ----------------
__global__ void k_prep_w(const float* __restrict__ Wh, const float* __restrict__ Wo,
                         u16* __restrict__ BcatT, u16* __restrict__ WhoT,
                         u32* __restrict__ Wpack) {
  int idx = blockIdx.x * 256 + threadIdx.x;
  if (idx < 1024 * 512) {
    int n = idx >> 9, k = idx & 511;
    float v = (n < 512) ? Wh[k * 512 + n] : Wo[k * 512 + (n - 512)];
    BcatT[idx] = f2bu(v);
  } else if (idx < 1024 * 512 + 512 * 512) {
    int t = idx - 1024 * 512;
    int n = t >> 9, k = t & 511;
    WhoT[t] = f2bu(Wo[(512 + k) * 512 + n]);
  } else {
    int t = idx - (1024 * 512 + 512 * 512);
    int k2 = t >> 9, j = t & 511;
    u16 a = __half_as_ushort(__float2half(Wh[(512 + 2 * k2) * 512 + j]));
    u16 b = __half_as_ushort(__float2half(Wh[(512 + 2 * k2 + 1) * 512 + j]));
    Wpack[t] = (u32)a | ((u32)b << 16);
  }
}

// ---------------- bf16 MFMA GEMM: C[M x N] = A[M x 512] * BT[N x 512]^T ----------------
template <int MODE>
__global__ __launch_bounds__(256) void k_gemm(
    const u16* __restrict__ A, const u16* __restrict__ BT, int NX,
    __half* __restrict__ outH, u16* __restrict__ outB, float* __restrict__ outF,
    const __half* __restrict__ Uo, const float* __restrict__ biasH,
    const float* __restrict__ biasO) {
  __shared__ __align__(16) u16 As[128 * 64], Bs[128 * 64];
  const int bid = blockIdx.x;
  const int bn = bid % NX, bm = bid / NX;
  const int m0 = bm * 128, n0 = bn * 128;
  const int tid = threadIdx.x, w = tid >> 6, l = tid & 63;
  const int l15 = l & 15, lk = (l >> 4) << 3;
  f32x4 acc[4][4] = {};
  for (int kt = 0; kt < 8; ++kt) {
    const int k0 = kt * 64;
#pragma unroll
    for (int i = 0; i < 4; ++i) {
      int idx = w * 4 + i;
      int ob = idx * 1024 + l * 16;
      int row = ob >> 7, cb = ob & 127;
      int scb = cb ^ ((row & 7) << 4);
      gload_lds16((const char*)A + (size_t)(m0 + row) * 1024 + k0 * 2 + scb,
                  (char*)As + idx * 1024);
      gload_lds16((const char*)BT + (size_t)(n0 + row) * 1024 + k0 * 2 + scb,
                  (char*)Bs + idx * 1024);
    }
    __syncthreads();
    const int wr = (w >> 1) * 64, wc = (w & 1) * 64;
#pragma unroll
    for (int kk = 0; kk < 2; ++kk) {
      s16x8 af[4], bfr[4];
      const int kb = (kk * 32 + lk) * 2;
#pragma unroll
      for (int i = 0; i < 4; ++i) {
        int ar = wr + i * 16 + l15;
        af[i] = *(const s16x8*)((const char*)As + ar * 128 + (kb ^ ((ar & 7) << 4)));
        int br = wc + i * 16 + l15;
        bfr[i] = *(const s16x8*)((const char*)Bs + br * 128 + (kb ^ ((br & 7) << 4)));
      }
#pragma unroll
      for (int i = 0; i < 4; ++i)
#pragma unroll
        for (int jj = 0; jj < 4; ++jj)
          acc[i][jj] = __builtin_amdgcn_mfma_f32_16x16x32_bf16(af[i], bfr[jj], acc[i][jj], 0, 0, 0);
    }
    __syncthreads();
  }
#pragma unroll
  for (int i = 0; i < 4; ++i)
#pragma unroll
    for (int jj = 0; jj < 4; ++jj)
#pragma unroll
      for (int rr = 0; rr < 4; ++rr) {
        int row = m0 + (w >> 1) * 64 + i * 16 + ((l >> 4) << 2) + rr;
        int col = n0 + (w & 1) * 64 + jj * 16 + l15;
        float v = acc[i][jj][rr];
        if (MODE == 0) {
          float bsv = (col < 512) ? biasH[col] : biasO[col - 512];
          outH[(size_t)row * 1024 + col] = __float2half(v + bsv);
        } else {
          float o = fast_tanh(v + __half2float(Uo[(size_t)row * 1024 + col]));
          if (MODE == 1) outB[(size_t)row * 512 + col] = f2bu(o);
          else           outF[(size_t)row * 512 + col] = o;
        }
      }
}

// ---------------- recurrent scan: one workgroup per batch row ----------------
// All weights resident: 184 k2-pairs in VGPRs (forced 256-VGPR alloc), 72 in
// dynamic LDS (144KB). 1 barrier/step (double-buffered h). Uh prefetched 1
// step ahead. No streamed weights.
#define REG_P 184          // k2-pairs in registers
#define LDS_GRP 18         // 18 groups x 4 pairs = 72 k2-pairs in LDS
#define SCAN_LDS_BYTES (LDS_GRP * 2048 * 4 + 2048)  // 147456 W + 2KB h dbuf

__global__ __launch_bounds__(512) __attribute__((amdgpu_waves_per_eu(2, 2)))
void k_scan(const u32* __restrict__ Wpack, const __half* __restrict__ Uh,
            const float* __restrict__ h0, u16* __restrict__ Hseq) {
  extern __shared__ __align__(16) u32 smem[];
  u32* Wl = smem;                                   // [18][512 threads][4] u32
  __half* hb = (__half*)(smem + LDS_GRP * 2048);    // 2 x 512 halves
  const int b = blockIdx.x, j = threadIdx.x;
  u32 wreg[REG_P];
#pragma unroll
  for (int p = 0; p < REG_P; ++p) wreg[p] = Wpack[p * 512 + j];
  for (int g = 0; g < LDS_GRP; ++g)
#pragma unroll
    for (int q = 0; q < 4; ++q)
      Wl[g * 2048 + j * 4 + q] = Wpack[(REG_P + 4 * g + q) * 512 + j];
  float h = h0 ? h0[b * 512 + j] : 0.f;
  hb[j] = __float2half(h);
  __syncthreads();
  const int r0 = b * T_STEPS;
  float u_cur = __half2float(Uh[(size_t)r0 * 1024 + j]);
  for (int t = 0; t < T_STEPS; ++t) {
    const int r = r0 + t;
    const int rn = (t < T_STEPS - 1) ? r + 1 : r;
    float u_nxt = __half2float(Uh[(size_t)rn * 1024 + j]);   // prefetch (overlaps dots)
    Hseq[(size_t)r * 512 + j] = f2bu(h);                     // h_in at step t
    const uint4* h4 = (const uint4*)(hb + (t & 1) * 512);
    float acc = u_cur;
#pragma unroll
    for (int g = 0; g < 46; ++g) {
      uint4 hv = h4[g];
      acc = fdot2u(wreg[4 * g + 0], hv.x, acc);
      acc = fdot2u(wreg[4 * g + 1], hv.y, acc);
      acc = fdot2u(wreg[4 * g + 2], hv.z, acc);
      acc = fdot2u(wreg[4 * g + 3], hv.w, acc);
    }
#pragma unroll
    for (int g = 0; g < LDS_GRP; ++g) {
      uint4 hv = h4[46 + g];
      uint4 wv = *(const uint4*)&Wl[g * 2048 + j * 4];
      acc = fdot2u(wv.x, hv.x, acc);
      acc = fdot2u(wv.y, hv.y, acc);
      acc = fdot2u(wv.z, hv.z, acc);
      acc = fdot2u(wv.w, hv.w, acc);
    }
    float hn = fast_tanh(acc);
    hb[((t + 1) & 1) * 512 + j] = __float2half(hn);
    h = hn;
    u_cur = u_nxt;
    __syncthreads();
  }
}

// ---------------- launch ----------------
extern "C" void kernel_launch(void* const* d_in, const int* in_sizes, int n_in,
                              void* d_out, int out_size, void* d_ws, size_t ws_size,
                              hipStream_t stream) {
  const float* x   = (const float*)d_in[0];
  const float* enc = (const float*)d_in[1];
  const float* Wh0 = (const float*)d_in[2];
  const float* bh0 = (const float*)d_in[3];
  const float* Wo0 = (const float*)d_in[4];
  const float* bo0 = (const float*)d_in[5];
  const float* Wh1 = (const float*)d_in[6];
  const float* bh1 = (const float*)d_in[7];
  const float* Wo1 = (const float*)d_in[8];
  const float* bo1 = (const float*)d_in[9];
  char* ws = (char*)d_ws;
  u16*    Xbf   = (u16*)(ws);
  __half* U     = (__half*)(ws + 16777216);
  u16*    Hs0   = (u16*)(ws + 16777216 + 33554432);
  u16*    Out0  = (u16*)(ws + 16777216 + 33554432 + 16777216);
  u16*    Hs1   = (u16*)(ws + 16777216 + 33554432 + 2 * 16777216);
  char*   wb    = ws + 16777216 + 33554432 + 3 * 16777216;
  u16*    Bct0  = (u16*)(wb);
  u16*    WhoT0 = (u16*)(wb + 1048576);
  u32*    Wpk0  = (u32*)(wb + 1048576 + 524288);
  u16*    Bct1  = (u16*)(wb + 1048576 + 2 * 524288);
  u16*    WhoT1 = (u16*)(wb + 2 * 1048576 + 2 * 524288);
  u32*    Wpk1  = (u32*)(wb + 2 * 1048576 + 3 * 524288);

  (void)hipFuncSetAttribute((const void*)k_scan,
                            hipFuncAttributeMaxDynamicSharedMemorySize,
                            SCAN_LDS_BYTES);

  k_cvt_bf16<<<8192, 256, 0, stream>>>(x, Xbf, 8388608 / 4);
  k_prep_w<<<3584, 256, 0, stream>>>(Wh0, Wo0, Bct0, WhoT0, Wpk0);
  k_prep_w<<<3584, 256, 0, stream>>>(Wh1, Wo1, Bct1, WhoT1, Wpk1);
  k_gemm<0><<<1024, 256, 0, stream>>>(Xbf, Bct0, 8, U, nullptr, nullptr, nullptr, bh0, bo0);
  k_scan<<<64, 512, SCAN_LDS_BYTES, stream>>>(Wpk0, U, enc, Hs0);
  k_gemm<1><<<512, 256, 0, stream>>>(Hs0, WhoT0, 4, nullptr, Out0, nullptr, U + 512, nullptr, nullptr);
  k_gemm<0><<<1024, 256, 0, stream>>>(Out0, Bct1, 8, U, nullptr, nullptr, nullptr, bh1, bo1);
  k_scan<<<64, 512, SCAN_LDS_BYTES, stream>>>(Wpk1, U, nullptr, Hs1);
  k_gemm<2><<<512, 256, 0, stream>>>(Hs1, WhoT1, 4, nullptr, nullptr, (float*)d_out, U + 512, nullptr, nullptr);
}

// Round 3
// 1026.695 us; speedup vs baseline: 1.0704x; 1.0210x over previous
//
#include <hip/hip_runtime.h>
#include <hip/hip_bf16.h>
#include <hip/hip_fp16.h>

typedef unsigned int u32;
typedef unsigned short u16;
typedef short s16x8 __attribute__((ext_vector_type(8)));
typedef float f32x4 __attribute__((ext_vector_type(4)));
typedef _Float16 f16x2 __attribute__((ext_vector_type(2)));

#define T_STEPS 256

// ---------------- helpers ----------------
__device__ __forceinline__ u16 f2bu(float f) {
  return __bfloat16_as_ushort(__float2bfloat16(f));
}
__device__ __forceinline__ float fast_tanh(float x) {
  float ax = fabsf(x);
  float e = __expf(-2.f * ax);
  float r = 1.f - 2.f * e / (1.f + e);
  return copysignf(r, x);
}
__device__ __forceinline__ __half2 bch2(u32 v) {
  return __builtin_bit_cast(__half2, v);
}
__device__ __forceinline__ void gload_lds16(const void* g, void* l) {
  __builtin_amdgcn_global_load_lds((const __attribute__((address_space(1))) u32*)g,
                                   (__attribute__((address_space(3))) u32*)l, 16, 0, 0);
}

// ---------------- x f32 -> bf16 ----------------
__global__ void k_cvt_bf16(const float* __restrict__ in, u16* __restrict__ out, int n4) {
  int i = blockIdx.x * blockDim.x + threadIdx.x;
  if (i >= n4) return;
  const float4 v = ((const float4*)in)[i];
  ushort4 o;
  o.x = f2bu(v.x); o.y = f2bu(v.y); o.z = f2bu(v.z); o.w = f2bu(v.w);
  ((ushort4*)out)[i] = o;
}

// ---------------- weight prep (per layer) ----------------
__global__ void k_prep_w(const float* __restrict__ Wh, const float* __restrict__ Wo,
                         u16* __restrict__ BcatT, u16* __restrict__ WhoT,
                         u32* __restrict__ Wpack) {
  int idx = blockIdx.x * 256 + threadIdx.x;
  if (idx < 1024 * 512) {
    int n = idx >> 9, k = idx & 511;
    float v = (n < 512) ? Wh[k * 512 + n] : Wo[k * 512 + (n - 512)];
    BcatT[idx] = f2bu(v);
  } else if (idx < 1024 * 512 + 512 * 512) {
    int t = idx - 1024 * 512;
    int n = t >> 9, k = t & 511;
    WhoT[t] = f2bu(Wo[(512 + k) * 512 + n]);
  } else {
    int t = idx - (1024 * 512 + 512 * 512);
    int k2 = t >> 9, j = t & 511;
    u16 a = __half_as_ushort(__float2half(Wh[(512 + 2 * k2) * 512 + j]));
    u16 b = __half_as_ushort(__float2half(Wh[(512 + 2 * k2 + 1) * 512 + j]));
    Wpack[t] = (u32)a | ((u32)b << 16);
  }
}

// ---------------- bf16 MFMA GEMM: C[M x N] = A[M x 512] * BT[N x 512]^T ----------------
template <int MODE>
__global__ __launch_bounds__(256) void k_gemm(
    const u16* __restrict__ A, const u16* __restrict__ BT, int NX,
    __half* __restrict__ outH, u16* __restrict__ outB, float* __restrict__ outF,
    const __half* __restrict__ Uo, const float* __restrict__ biasH,
    const float* __restrict__ biasO) {
  __shared__ __align__(16) u16 As[128 * 64], Bs[128 * 64];
  const int bid = blockIdx.x;
  const int bn = bid % NX, bm = bid / NX;
  const int m0 = bm * 128, n0 = bn * 128;
  const int tid = threadIdx.x, w = tid >> 6, l = tid & 63;
  const int l15 = l & 15, lk = (l >> 4) << 3;
  f32x4 acc[4][4] = {};
  for (int kt = 0; kt < 8; ++kt) {
    const int k0 = kt * 64;
#pragma unroll
    for (int i = 0; i < 4; ++i) {
      int idx = w * 4 + i;
      int ob = idx * 1024 + l * 16;
      int row = ob >> 7, cb = ob & 127;
      int scb = cb ^ ((row & 7) << 4);
      gload_lds16((const char*)A + (size_t)(m0 + row) * 1024 + k0 * 2 + scb,
                  (char*)As + idx * 1024);
      gload_lds16((const char*)BT + (size_t)(n0 + row) * 1024 + k0 * 2 + scb,
                  (char*)Bs + idx * 1024);
    }
    __syncthreads();
    const int wr = (w >> 1) * 64, wc = (w & 1) * 64;
#pragma unroll
    for (int kk = 0; kk < 2; ++kk) {
      s16x8 af[4], bfr[4];
      const int kb = (kk * 32 + lk) * 2;
#pragma unroll
      for (int i = 0; i < 4; ++i) {
        int ar = wr + i * 16 + l15;
        af[i] = *(const s16x8*)((const char*)As + ar * 128 + (kb ^ ((ar & 7) << 4)));
        int br = wc + i * 16 + l15;
        bfr[i] = *(const s16x8*)((const char*)Bs + br * 128 + (kb ^ ((br & 7) << 4)));
      }
#pragma unroll
      for (int i = 0; i < 4; ++i)
#pragma unroll
        for (int jj = 0; jj < 4; ++jj)
          acc[i][jj] = __builtin_amdgcn_mfma_f32_16x16x32_bf16(af[i], bfr[jj], acc[i][jj], 0, 0, 0);
    }
    __syncthreads();
  }
#pragma unroll
  for (int i = 0; i < 4; ++i)
#pragma unroll
    for (int jj = 0; jj < 4; ++jj)
#pragma unroll
      for (int rr = 0; rr < 4; ++rr) {
        int row = m0 + (w >> 1) * 64 + i * 16 + ((l >> 4) << 2) + rr;
        int col = n0 + (w & 1) * 64 + jj * 16 + l15;
        float v = acc[i][jj][rr];
        if (MODE == 0) {
          float bsv = (col < 512) ? biasH[col] : biasO[col - 512];
          outH[(size_t)row * 1024 + col] = __float2half(v + bsv);
        } else {
          float o = fast_tanh(v + __half2float(Uo[(size_t)row * 1024 + col]));
          if (MODE == 1) outB[(size_t)row * 512 + col] = f2bu(o);
          else           outF[(size_t)row * 512 + col] = o;
        }
      }
}

// ---------------- recurrent scan: one workgroup per batch row ----------------
// 192 k2-pairs in VGPRs + 64 pairs in LDS (131KB). pk_fma_f16 full-rate dots,
// 4 independent accumulator chains, 1 barrier/step, Uh prefetched 1 ahead.
#define REG_P 192
#define LDS_GRP 16                                   // 16 groups x 4 pairs in LDS
#define SCAN_LDS_BYTES (LDS_GRP * 8192 + 2048)       // 131072 W + 2KB h dbuf

__global__ __launch_bounds__(512, 2)
void k_scan(const u32* __restrict__ Wpack, const __half* __restrict__ Uh,
            const float* __restrict__ h0, u16* __restrict__ Hseq) {
  extern __shared__ __align__(16) u32 smem[];
  u32* Wl = smem;                                    // [16][512 threads][4] u32
  __half* hb = (__half*)(smem + LDS_GRP * 2048);     // 2 x 512 halves
  const int b = blockIdx.x, j = threadIdx.x;
  u32 wreg[REG_P];
#pragma unroll
  for (int p = 0; p < REG_P; ++p) wreg[p] = Wpack[p * 512 + j];
#pragma unroll
  for (int g = 0; g < LDS_GRP; ++g)
#pragma unroll
    for (int q = 0; q < 4; ++q)
      Wl[g * 2048 + j * 4 + q] = Wpack[(REG_P + 4 * g + q) * 512 + j];
  float h = h0 ? h0[b * 512 + j] : 0.f;
  hb[j] = __float2half(h);
  __syncthreads();
  const int r0 = b * T_STEPS;
  float u_cur = __half2float(Uh[(size_t)r0 * 1024 + j]);
  for (int t = 0; t < T_STEPS; ++t) {
    const int r = r0 + t;
    const int rn = (t < T_STEPS - 1) ? r + 1 : r;
    float u_nxt = __half2float(Uh[(size_t)rn * 1024 + j]);   // prefetch
    Hseq[(size_t)r * 512 + j] = f2bu(h);                     // h_in at step t
    const uint4* h4 = (const uint4*)(hb + (t & 1) * 512);
    __half2 a0 = __float2half2_rn(0.f), a1 = a0, a2 = a0, a3 = a0;
#pragma unroll
    for (int g = 0; g < 48; ++g) {
      uint4 hv = h4[g];
      a0 = __hfma2(bch2(wreg[4 * g + 0]), bch2(hv.x), a0);
      a1 = __hfma2(bch2(wreg[4 * g + 1]), bch2(hv.y), a1);
      a2 = __hfma2(bch2(wreg[4 * g + 2]), bch2(hv.z), a2);
      a3 = __hfma2(bch2(wreg[4 * g + 3]), bch2(hv.w), a3);
    }
#pragma unroll
    for (int g = 0; g < LDS_GRP; ++g) {
      uint4 hv = h4[48 + g];
      uint4 wv = *(const uint4*)&Wl[g * 2048 + j * 4];
      a0 = __hfma2(bch2(wv.x), bch2(hv.x), a0);
      a1 = __hfma2(bch2(wv.y), bch2(hv.y), a1);
      a2 = __hfma2(bch2(wv.z), bch2(hv.z), a2);
      a3 = __hfma2(bch2(wv.w), bch2(hv.w), a3);
    }
    float acc = u_cur;
    acc += __low2float(a0) + __high2float(a0);
    acc += __low2float(a1) + __high2float(a1);
    acc += __low2float(a2) + __high2float(a2);
    acc += __low2float(a3) + __high2float(a3);
    float hn = fast_tanh(acc);
    hb[((t + 1) & 1) * 512 + j] = __float2half(hn);
    h = hn;
    u_cur = u_nxt;
    __syncthreads();
  }
}

// ---------------- launch ----------------
extern "C" void kernel_launch(void* const* d_in, const int* in_sizes, int n_in,
                              void* d_out, int out_size, void* d_ws, size_t ws_size,
                              hipStream_t stream) {
  const float* x   = (const float*)d_in[0];
  const float* enc = (const float*)d_in[1];
  const float* Wh0 = (const float*)d_in[2];
  const float* bh0 = (const float*)d_in[3];
  const float* Wo0 = (const float*)d_in[4];
  const float* bo0 = (const float*)d_in[5];
  const float* Wh1 = (const float*)d_in[6];
  const float* bh1 = (const float*)d_in[7];
  const float* Wo1 = (const float*)d_in[8];
  const float* bo1 = (const float*)d_in[9];
  char* ws = (char*)d_ws;
  u16*    Xbf   = (u16*)(ws);
  __half* U     = (__half*)(ws + 16777216);
  u16*    Hs0   = (u16*)(ws + 16777216 + 33554432);
  u16*    Out0  = (u16*)(ws + 16777216 + 33554432 + 16777216);
  u16*    Hs1   = (u16*)(ws + 16777216 + 33554432 + 2 * 16777216);
  char*   wb    = ws + 16777216 + 33554432 + 3 * 16777216;
  u16*    Bct0  = (u16*)(wb);
  u16*    WhoT0 = (u16*)(wb + 1048576);
  u32*    Wpk0  = (u32*)(wb + 1048576 + 524288);
  u16*    Bct1  = (u16*)(wb + 1048576 + 2 * 524288);
  u16*    WhoT1 = (u16*)(wb + 2 * 1048576 + 2 * 524288);
  u32*    Wpk1  = (u32*)(wb + 2 * 1048576 + 3 * 524288);

  (void)hipFuncSetAttribute((const void*)k_scan,
                            hipFuncAttributeMaxDynamicSharedMemorySize,
                            SCAN_LDS_BYTES);

  k_cvt_bf16<<<8192, 256, 0, stream>>>(x, Xbf, 8388608 / 4);
  k_prep_w<<<3584, 256, 0, stream>>>(Wh0, Wo0, Bct0, WhoT0, Wpk0);
  k_prep_w<<<3584, 256, 0, stream>>>(Wh1, Wo1, Bct1, WhoT1, Wpk1);
  k_gemm<0><<<1024, 256, 0, stream>>>(Xbf, Bct0, 8, U, nullptr, nullptr, nullptr, bh0, bo0);
  k_scan<<<64, 512, SCAN_LDS_BYTES, stream>>>(Wpk0, U, enc, Hs0);
  k_gemm<1><<<512, 256, 0, stream>>>(Hs0, WhoT0, 4, nullptr, Out0, nullptr, U + 512, nullptr, nullptr);
  k_gemm<0><<<1024, 256, 0, stream>>>(Out0, Bct1, 8, U, nullptr, nullptr, nullptr, bh1, bo1);
  k_scan<<<64, 512, SCAN_LDS_BYTES, stream>>>(Wpk1, U, nullptr, Hs1);
  k_gemm<2><<<512, 256, 0, stream>>>(Hs1, WhoT1, 4, nullptr, nullptr, (float*)d_out, U + 512, nullptr, nullptr);
}